// Round 10
// baseline (5657.755 us; speedup 1.0000x reference)
//
#include <hip/hip_runtime.h>
#include <cmath>

#define BATCH 2048
#define TSTEPS 16384

#define L2E 1.4426950408889634074
#define DTC 0.02

// Uniform per-slot rate form (DT and log2e folded):
//   e = 2^(A2*V + B2);   r' = DT*rate = (Cd + Dd*V) * e / (P + Q*e)
// slots: 0=alpha_m 1=beta_m 2=alpha_h 3=beta_h 4=alpha_n 5=beta_n 6,7=spare
__device__ __constant__ double CA2[8] = {0.1*L2E, -(1.0/18.0)*L2E, -0.05*L2E, 0.1*L2E, 0.1*L2E, -0.0125*L2E, 0.0, 0.0};
__device__ __constant__ double CB2[8] = {4.0*L2E, -(65.0/18.0)*L2E, -3.25*L2E, 3.5*L2E, 5.5*L2E, -0.8125*L2E, 0.0, 0.0};
__device__ __constant__ double CCd[8] = {DTC*4.0, DTC*4.0, DTC*0.07, DTC*1.0, DTC*0.55, DTC*0.125, DTC, DTC};
__device__ __constant__ double CDd[8] = {DTC*0.1, 0.0, 0.0, 0.0, DTC*0.01, 0.0, 0.0, 0.0};
__device__ __constant__ double CP[8]  = {-1.0, 1.0, 1.0, 1.0, -1.0, 1.0, 1.0, 1.0};
__device__ __constant__ double CQ[8]  = {1.0+1e-8, 0.0, 0.0, 1.0, 1.0+1e-8, 0.0, 0.0, 0.0};
__device__ __constant__ double CFV[8] = {-40.0, 1e300, 1e300, 1e300, -55.0, 1e300, 1e300, 1e300};
__device__ __constant__ double CFR[8] = {DTC*1.0, 0.0, 0.0, 0.0, DTC*0.1, 0.0, 0.0, 0.0};

__device__ __forceinline__ float hw_exp2(float x) {
#if __has_builtin(__builtin_amdgcn_exp2f)
    return __builtin_amdgcn_exp2f(x);
#else
    float r; asm("v_exp_f32 %0, %1" : "=v"(r) : "v"(x)); return r;
#endif
}
__device__ __forceinline__ float rcp32(float d) {
#if __has_builtin(__builtin_amdgcn_rcpf)
    float x = __builtin_amdgcn_rcpf(d);
#else
    float x; asm("v_rcp_f32 %0, %1" : "=v"(x) : "v"(d));
#endif
    return fmaf(x, fmaf(-d, x, 1.0f), x);   // 1 NR: ~0.5 ulp
}

// f64 lane exchange within 8-groups via ds_swizzle (BitMode, wave-scoped)
template<int PAT>
__device__ __forceinline__ double swz_f64(double v) {
    int lo = __builtin_amdgcn_ds_swizzle(__double2loint(v), PAT);
    int hi = __builtin_amdgcn_ds_swizzle(__double2hiint(v), PAT);
    return __hiloint2double(hi, lo);
}
#define SWZ_XOR1  0x041F              // lane ^ 1
#define SWZ_BC(k) (((k) << 5) | 0x18) // broadcast lane (base|k) within 8-group

__global__ __launch_bounds__(1024)
void hh8u_kernel(const float* __restrict__ I,
                 const float* __restrict__ rgNa,
                 const float* __restrict__ rgK,
                 const float* __restrict__ rgL,
                 float* __restrict__ out)
{
    const int gid  = blockIdx.x * 1024 + threadIdx.x;
    const int slot = gid & 7;
    const int nb   = gid >> 3;                  // neuron index
    const bool canc = (slot == 0) || (slot == 4);   // den = e-1+eps slots

    const double A2 = CA2[slot], B2 = CB2[slot];
    const double Cd = CCd[slot], Dd = CDd[slot];
    const double fixV = CFV[slot];
    const float  P32 = (float)CP[slot], Q32 = (float)CQ[slot];
    const float  fixR32 = (float)CFR[slot];

    // softplus(x) = max(x,0) + log1p(exp(-|x|))
    double gNa, gK, gL;
    {
        double x = (double)rgNa[0]; gNa = fmax(x, 0.0) + log1p(exp(-fabs(x)));
        x = (double)rgK[0];         gK  = fmax(x, 0.0) + log1p(exp(-fabs(x)));
        x = (double)rgL[0];         gL  = fmax(x, 0.0) + log1p(exp(-fabs(x)));
    }
    const double kNa = DTC * gNa;
    const double kK  = DTC * gK;
    const double K1  = 1.0 - DTC * gL;
    const double K2  = -54.387 * (DTC * gL);

    // Mixed-precision rate (r8-proven): f64 argument + exact range reduction,
    // hw f32 exp2 of the fraction, exponent injection, NR'd rcp.  Cancellation
    // slots use 2^t-1 = t*P(t) when i==0 so den keeps ~5e-7 rel err near 0.
    auto rate = [&](double Vx) -> float {
        const double C52 = 6755399441055744.0;   // 1.5*2^52
        double y  = fma(A2, Vx, B2);
        double z  = y + C52;
        double nf = z - C52;                     // round-to-nearest(y)
        double t  = y - nf;                      // exact, [-0.5, 0.5]
        int    i  = __double2loint(z);
        float  t32 = (float)t;
        float  p32 = hw_exp2(t32);               // 2^t, ~1 ulp
        float  e32 = __int_as_float(__float_as_int(p32) + (i << 23));  // *2^i
        // (2^t - 1)/t  Taylor, f32:
        float P5 = fmaf(t32, 1.5403530e-4f, 1.3333558e-3f);
        P5 = fmaf(t32, P5, 9.6181291e-3f);
        P5 = fmaf(t32, P5, 5.5504109e-2f);
        P5 = fmaf(t32, P5, 2.4022651e-1f);
        P5 = fmaf(t32, P5, 6.9314718e-1f);
        float em1 = t32 * P5;                    // 2^t - 1, full rel precision
        float den_a = fmaf(Q32, e32, P32);
        float den_b = fmaf(1e-8f, e32, em1);     // e-1+1e-8e without cancellation
        float den = (canc && (i == 0)) ? den_b : den_a;
        float num = (float)fma(Dd, Vx, Cd) * e32;
        float r0  = num * rcp32(den);
        return (fabs(Vx - fixV) < 1e-6) ? fixR32 : r0;
    };

    double V = -65.0;
    float  r = rate(V);                  // pipelined: r == DT*rate(V_cur), f32
    double g, m, h, n;                   // g = own gate (valid on even lanes)
    {
        float rbf = __int_as_float(__builtin_amdgcn_ds_swizzle(__float_as_int(r), SWZ_XOR1));
        double rd = (double)r, rbd = (double)rbf;
        g = rd / (rd + rbd);             // alpha/(alpha+beta) on even lanes
        m = swz_f64<SWZ_BC(0)>(g);
        h = swz_f64<SWZ_BC(2)>(g);
        n = swz_f64<SWZ_BC(4)>(g);
    }

    const float* __restrict__ Ip = I + (size_t)nb * TSTEPS;
    float*       __restrict__ Op = out + (size_t)nb * TSTEPS + slot;

    // r5-proven step order: xor early, V-update (old gates), gate commit,
    // broadcasts (covered by rate chain), rate last.
    auto step = [&](float It) {
        float rbf = __int_as_float(__builtin_amdgcn_ds_swizzle(__float_as_int(r), SWZ_XOR1));
        // ---- V-update from OLD gates (f64) ----
        double mm  = m * m,  mh = m * h;
        double m3h = mm * mh;
        double nn  = n * n;
        double n4  = nn * nn;
        double a   = kNa * m3h;
        double b   = kK * n4;
        double S1  = (K1 - a) - b;
        double S2  = fma(-77.0, b, fma(50.0, a, K2));
        double Vn  = fma(V, S1, fma(DTC, (double)It, S2));
        // ---- gate update on own lane (f64, rates promoted) ----
        double rd  = (double)r, rbd = (double)rbf;
        double sr  = rd + rbd;
        g = fma(-sr, g, g + rd);
        // ---- broadcast new gates (latency covered by rate chain below) ----
        m = swz_f64<SWZ_BC(0)>(g);
        h = swz_f64<SWZ_BC(2)>(g);
        n = swz_f64<SWZ_BC(4)>(g);
        // ---- next-step rate (short mixed-precision chain) ----
        r = rate(Vn);
        V = Vn;
    };

    const int NCH = TSTEPS / 8;
    float4 ia = reinterpret_cast<const float4*>(Ip)[0];
    float4 ib = reinterpret_cast<const float4*>(Ip)[1];

    for (int c = 0; c < NCH - 1; ++c) {
        const float cur[8] = {ia.x, ia.y, ia.z, ia.w, ib.x, ib.y, ib.z, ib.w};
        ia = reinterpret_cast<const float4*>(Ip)[2 * (c + 1)];
        ib = reinterpret_cast<const float4*>(Ip)[2 * (c + 1) + 1];
        float vs = 0.0f;
        #pragma unroll
        for (int j = 0; j < 8; ++j) {
            vs = (slot == j) ? (float)V : vs;   // out[p] = V after p steps
            step(cur[j]);
        }
        Op[c * 8] = vs;
    }
    // epilogue chunk: save 8 positions, step only the first 7 (I[T-1] unused)
    {
        const float cur[8] = {ia.x, ia.y, ia.z, ia.w, ib.x, ib.y, ib.z, ib.w};
        float vs = 0.0f;
        #pragma unroll
        for (int j = 0; j < 8; ++j) {
            vs = (slot == j) ? (float)V : vs;
            if (j < 7) step(cur[j]);
        }
        Op[(NCH - 1) * 8] = vs;
    }
}

extern "C" void kernel_launch(void* const* d_in, const int* in_sizes, int n_in,
                              void* d_out, int out_size, void* d_ws, size_t ws_size,
                              hipStream_t stream) {
    const float* I    = (const float*)d_in[0];
    const float* rgNa = (const float*)d_in[1];
    const float* rgK  = (const float*)d_in[2];
    const float* rgL  = (const float*)d_in[3];
    float* out = (float*)d_out;

    // 16 blocks x 1024 threads = 16384 threads = 2048 neurons x 8 slots.
    // 16 waves/block -> 4 waves per SIMD on 16 CUs: co-resident waves fill
    // each other's f64 dependency-gap stalls (issue demand 4x60% >> 100%).
    hh8u_kernel<<<dim3(BATCH * 8 / 1024), dim3(1024), 0, stream>>>(I, rgNa, rgK, rgL, out);
}

// Round 11
// 2614.072 us; speedup vs baseline: 2.1643x; 2.1643x over previous
//
#include <hip/hip_runtime.h>
#include <cmath>

#define BATCH 2048
#define TSTEPS 16384

#define L2E 1.4426950408889634074
#define DTC 0.02

// Uniform per-slot rate form (DT and log2e folded):
//   e = 2^(A2*V + B2);   r' = DT*rate = (Cd + Dd*V) * e / (P + Q*e)
// slots: 0=alpha_m 1=beta_m 2=alpha_h 3=beta_h 4=alpha_n 5=beta_n 6,7=spare
__device__ __constant__ double CA2[8] = {0.1*L2E, -(1.0/18.0)*L2E, -0.05*L2E, 0.1*L2E, 0.1*L2E, -0.0125*L2E, 0.0, 0.0};
__device__ __constant__ double CB2[8] = {4.0*L2E, -(65.0/18.0)*L2E, -3.25*L2E, 3.5*L2E, 5.5*L2E, -0.8125*L2E, 0.0, 0.0};
__device__ __constant__ double CCd[8] = {DTC*4.0, DTC*4.0, DTC*0.07, DTC*1.0, DTC*0.55, DTC*0.125, DTC, DTC};
__device__ __constant__ double CDd[8] = {DTC*0.1, 0.0, 0.0, 0.0, DTC*0.01, 0.0, 0.0, 0.0};
__device__ __constant__ double CP[8]  = {-1.0, 1.0, 1.0, 1.0, -1.0, 1.0, 1.0, 1.0};
__device__ __constant__ double CQ[8]  = {1.0+1e-8, 0.0, 0.0, 1.0, 1.0+1e-8, 0.0, 0.0, 0.0};
__device__ __constant__ double CFV[8] = {-40.0, 1e300, 1e300, 1e300, -55.0, 1e300, 1e300, 1e300};
__device__ __constant__ double CFR[8] = {DTC*1.0, 0.0, 0.0, 0.0, DTC*0.1, 0.0, 0.0, 0.0};

__device__ __forceinline__ float hw_exp2(float x) {
#if __has_builtin(__builtin_amdgcn_exp2f)
    return __builtin_amdgcn_exp2f(x);
#else
    float r; asm("v_exp_f32 %0, %1" : "=v"(r) : "v"(x)); return r;
#endif
}
__device__ __forceinline__ float rcp32(float d) {
#if __has_builtin(__builtin_amdgcn_rcpf)
    float x = __builtin_amdgcn_rcpf(d);
#else
    float x; asm("v_rcp_f32 %0, %1" : "=v"(x) : "v"(d));
#endif
    return fmaf(x, fmaf(-d, x, 1.0f), x);   // 1 NR: ~0.5 ulp
}

// f32 broadcast from lane (groupbase|k) within each 8-lane group (BitMode)
template<int PAT>
__device__ __forceinline__ float swz_f32(float v) {
    return __int_as_float(__builtin_amdgcn_ds_swizzle(__float_as_int(v), PAT));
}
#define SWZ_BC(k) (((k) << 5) | 0x18) // src = (lane & 0x18) | k

__global__ __launch_bounds__(64, 1)
void hh8v_kernel(const float* __restrict__ I,
                 const float* __restrict__ rgNa,
                 const float* __restrict__ rgK,
                 const float* __restrict__ rgL,
                 float* __restrict__ out)
{
    const int lane = threadIdx.x;               // block == 1 wave
    const int slot = lane & 7;
    const int nb   = blockIdx.x * 8 + (lane >> 3);
    const bool canc = (slot == 0) || (slot == 4);   // den = e-1+eps slots

    const double A2 = CA2[slot], B2 = CB2[slot];
    const double Cd = CCd[slot], Dd = CDd[slot];
    const double fixV = CFV[slot];
    const float  P32 = (float)CP[slot], Q32 = (float)CQ[slot];
    const float  fixR32 = (float)CFR[slot];

    // softplus(x) = max(x,0) + log1p(exp(-|x|))
    double gNa, gK, gL;
    {
        double x = (double)rgNa[0]; gNa = fmax(x, 0.0) + log1p(exp(-fabs(x)));
        x = (double)rgK[0];         gK  = fmax(x, 0.0) + log1p(exp(-fabs(x)));
        x = (double)rgL[0];         gL  = fmax(x, 0.0) + log1p(exp(-fabs(x)));
    }
    const double kNa = DTC * gNa;
    const double kK  = DTC * gK;
    const double K1  = 1.0 - DTC * gL;
    const double K2  = -54.387 * (DTC * gL);

    // Mixed-precision rate (r8-proven, bit-identical): f64 argument + exact
    // magic-number range reduction, hw f32 exp2, exponent injection, NR'd rcp.
    auto rate = [&](double Vx) -> float {
        const double C52 = 6755399441055744.0;   // 1.5*2^52
        double y  = fma(A2, Vx, B2);
        double z  = y + C52;
        double nf = z - C52;                     // round-to-nearest(y)
        double t  = y - nf;                      // exact, [-0.5, 0.5]
        int    i  = __double2loint(z);
        float  t32 = (float)t;
        float  p32 = hw_exp2(t32);               // 2^t, ~1 ulp
        float  e32 = __int_as_float(__float_as_int(p32) + (i << 23));  // *2^i
        // (2^t - 1)/t  Taylor, f32 (cancellation-free den for slots 0,4):
        float P5 = fmaf(t32, 1.5403530e-4f, 1.3333558e-3f);
        P5 = fmaf(t32, P5, 9.6181291e-3f);
        P5 = fmaf(t32, P5, 5.5504109e-2f);
        P5 = fmaf(t32, P5, 2.4022651e-1f);
        P5 = fmaf(t32, P5, 6.9314718e-1f);
        float em1 = t32 * P5;                    // 2^t - 1, full rel precision
        float den_a = fmaf(Q32, e32, P32);
        float den_b = fmaf(1e-8f, e32, em1);     // e-1+1e-8e without cancellation
        float den = (canc && (i == 0)) ? den_b : den_a;
        float num = (float)fma(Dd, Vx, Cd) * e32;
        float r0  = num * rcp32(den);
        return (fabs(Vx - fixV) < 1e-6) ? fixR32 : r0;
    };

    double V = -65.0;
    float  r = rate(V);                  // pipelined: r == DT*rate(V_cur), own slot
    double m, h, n;                      // gates replicated on ALL lanes (f64)
    {
        float b0 = swz_f32<SWZ_BC(0)>(r), b1 = swz_f32<SWZ_BC(1)>(r);
        float b2 = swz_f32<SWZ_BC(2)>(r), b3 = swz_f32<SWZ_BC(3)>(r);
        float b4 = swz_f32<SWZ_BC(4)>(r), b5 = swz_f32<SWZ_BC(5)>(r);
        m = (double)b0 / ((double)b0 + (double)b1);   // DT cancels in the ratio
        h = (double)b2 / ((double)b2 + (double)b3);
        n = (double)b4 / ((double)b4 + (double)b5);
    }

    const float* __restrict__ Ip = I + (size_t)nb * TSTEPS;
    float*       __restrict__ Op = out + (size_t)nb * TSTEPS + slot;

    // Step order: [bcast rates | V-update (old gates; covers ds latency) |
    //              local gate updates (all lanes) | rate(Vn) last].
    // Carried cycle loses r8's xor->commit->bcast double-stage.
    auto step = [&](float It) {
        // [1] broadcast this step's six rates (rates of V_k)
        float b0 = swz_f32<SWZ_BC(0)>(r), b1 = swz_f32<SWZ_BC(1)>(r);
        float b2 = swz_f32<SWZ_BC(2)>(r), b3 = swz_f32<SWZ_BC(3)>(r);
        float b4 = swz_f32<SWZ_BC(4)>(r), b5 = swz_f32<SWZ_BC(5)>(r);
        // [2] V-update from OLD gates (f64)
        double mm  = m * m,  mh = m * h;
        double m3h = mm * mh;
        double nn  = n * n;
        double n4  = nn * nn;
        double a   = kNa * m3h;
        double b   = kK * n4;
        double S1  = (K1 - a) - b;
        double S2  = fma(-77.0, b, fma(50.0, a, K2));
        double Vn  = fma(V, S1, fma(DTC, (double)It, S2));
        // [3] gate updates, replicated on every lane (f64-promoted, r8 rounding)
        double a0 = (double)b0, a1 = (double)b1;
        double a2 = (double)b2, a3 = (double)b3;
        double a4 = (double)b4, a5 = (double)b5;
        m = fma(-(a0 + a1), m, m + a0);
        h = fma(-(a2 + a3), h, h + a2);
        n = fma(-(a4 + a5), n, n + a4);
        // [4] next-step rate (long chain last; tail lands next step's [1])
        r = rate(Vn);
        V = Vn;
    };

    const int NCH = TSTEPS / 8;
    float4 ia = reinterpret_cast<const float4*>(Ip)[0];
    float4 ib = reinterpret_cast<const float4*>(Ip)[1];

    for (int c = 0; c < NCH - 1; ++c) {
        const float cur[8] = {ia.x, ia.y, ia.z, ia.w, ib.x, ib.y, ib.z, ib.w};
        ia = reinterpret_cast<const float4*>(Ip)[2 * (c + 1)];
        ib = reinterpret_cast<const float4*>(Ip)[2 * (c + 1) + 1];
        float vs = 0.0f;
        #pragma unroll
        for (int j = 0; j < 8; ++j) {
            vs = (slot == j) ? (float)V : vs;   // out[p] = V after p steps
            step(cur[j]);
        }
        Op[c * 8] = vs;
    }
    // epilogue chunk: save 8 positions, step only the first 7 (I[T-1] unused)
    {
        const float cur[8] = {ia.x, ia.y, ia.z, ia.w, ib.x, ib.y, ib.z, ib.w};
        float vs = 0.0f;
        #pragma unroll
        for (int j = 0; j < 8; ++j) {
            vs = (slot == j) ? (float)V : vs;
            if (j < 7) step(cur[j]);
        }
        Op[(NCH - 1) * 8] = vs;
    }
}

extern "C" void kernel_launch(void* const* d_in, const int* in_sizes, int n_in,
                              void* d_out, int out_size, void* d_ws, size_t ws_size,
                              hipStream_t stream) {
    const float* I    = (const float*)d_in[0];
    const float* rgNa = (const float*)d_in[1];
    const float* rgK  = (const float*)d_in[2];
    const float* rgL  = (const float*)d_in[3];
    float* out = (float*)d_out;

    hh8v_kernel<<<dim3(BATCH / 8), dim3(64), 0, stream>>>(I, rgNa, rgK, rgL, out);
}

// Round 12
// 2397.918 us; speedup vs baseline: 2.3594x; 1.0901x over previous
//
#include <hip/hip_runtime.h>
#include <cmath>

#define BATCH 2048
#define TSTEPS 16384

#define L2E 1.4426950408889634074
#define DTC 0.02

// Uniform per-slot rate form (DT and log2e folded):
//   e = 2^(A2*V + B2);   r' = DT*rate = (Cd + Dd*V) * e / (P + Q*e)
// slots: 0=alpha_m 1=beta_m 2=alpha_h 3=beta_h 4=alpha_n 5=beta_n 6,7=spare
__device__ __constant__ double CA2[8] = {0.1*L2E, -(1.0/18.0)*L2E, -0.05*L2E, 0.1*L2E, 0.1*L2E, -0.0125*L2E, 0.0, 0.0};
__device__ __constant__ double CB2[8] = {4.0*L2E, -(65.0/18.0)*L2E, -3.25*L2E, 3.5*L2E, 5.5*L2E, -0.8125*L2E, 0.0, 0.0};
__device__ __constant__ double CCd[8] = {DTC*4.0, DTC*4.0, DTC*0.07, DTC*1.0, DTC*0.55, DTC*0.125, DTC, DTC};
__device__ __constant__ double CDd[8] = {DTC*0.1, 0.0, 0.0, 0.0, DTC*0.01, 0.0, 0.0, 0.0};
__device__ __constant__ double CP[8]  = {-1.0, 1.0, 1.0, 1.0, -1.0, 1.0, 1.0, 1.0};
__device__ __constant__ double CQ[8]  = {1.0+1e-8, 0.0, 0.0, 1.0, 1.0+1e-8, 0.0, 0.0, 0.0};
__device__ __constant__ double CFV[8] = {-40.0, 1e300, 1e300, 1e300, -55.0, 1e300, 1e300, 1e300};
__device__ __constant__ double CFR[8] = {DTC*1.0, 0.0, 0.0, 0.0, DTC*0.1, 0.0, 0.0, 0.0};

__device__ __forceinline__ float hw_exp2(float x) {
#if __has_builtin(__builtin_amdgcn_exp2f)
    return __builtin_amdgcn_exp2f(x);
#else
    float r; asm("v_exp_f32 %0, %1" : "=v"(r) : "v"(x)); return r;
#endif
}
__device__ __forceinline__ float rcp32(float d) {
#if __has_builtin(__builtin_amdgcn_rcpf)
    float x = __builtin_amdgcn_rcpf(d);
#else
    float x; asm("v_rcp_f32 %0, %1" : "=v"(x) : "v"(d));
#endif
    return fmaf(x, fmaf(-d, x, 1.0f), x);   // 1 NR: ~0.5 ulp
}

// f64 lane exchange within 8-groups via ds_swizzle (BitMode)
template<int PAT>
__device__ __forceinline__ double swz_f64(double v) {
    int lo = __builtin_amdgcn_ds_swizzle(__double2loint(v), PAT);
    int hi = __builtin_amdgcn_ds_swizzle(__double2hiint(v), PAT);
    return __hiloint2double(hi, lo);
}
#define SWZ_XOR1  0x041F              // lane ^ 1
#define SWZ_BC(k) (((k) << 5) | 0x18) // broadcast lane (base|k) within 8-group

__global__ __launch_bounds__(64, 1)
void hh8t_kernel(const float* __restrict__ I,
                 const float* __restrict__ rgNa,
                 const float* __restrict__ rgK,
                 const float* __restrict__ rgL,
                 float* __restrict__ out)
{
    const int lane = threadIdx.x;               // block == 1 wave
    const int slot = lane & 7;
    const int nb   = blockIdx.x * 8 + (lane >> 3);
    const bool canc = (slot == 0) || (slot == 4);   // den = e-1+eps slots

    const double A2 = CA2[slot], B2 = CB2[slot];
    const double Cd = CCd[slot], Dd = CDd[slot];
    const double fixV = CFV[slot];
    const float  P32 = (float)CP[slot], Q32 = (float)CQ[slot];
    const float  fixR32 = (float)CFR[slot];

    // softplus(x) = max(x,0) + log1p(exp(-|x|))
    double gNa, gK, gL;
    {
        double x = (double)rgNa[0]; gNa = fmax(x, 0.0) + log1p(exp(-fabs(x)));
        x = (double)rgK[0];         gK  = fmax(x, 0.0) + log1p(exp(-fabs(x)));
        x = (double)rgL[0];         gL  = fmax(x, 0.0) + log1p(exp(-fabs(x)));
    }
    const double kNa = DTC * gNa;
    const double kK  = DTC * gK;
    const double K1  = 1.0 - DTC * gL;
    const double K2  = -54.387 * (DTC * gL);

    // Mixed-precision rate (r8-proven): f64 argument + exact range reduction,
    // hw f32 exp2 of the fraction, exponent injection, NR'd rcp.  Cancellation
    // slots use 2^t-1 = t*P(t) when i==0 so den keeps ~5e-7 rel err near 0.
    auto rate = [&](double Vx) -> float {
        const double C52 = 6755399441055744.0;   // 1.5*2^52
        double y  = fma(A2, Vx, B2);
        double z  = y + C52;
        double nf = z - C52;                     // round-to-nearest(y)
        double t  = y - nf;                      // exact, [-0.5, 0.5]
        int    i  = __double2loint(z);
        float  t32 = (float)t;
        float  p32 = hw_exp2(t32);               // 2^t, ~1 ulp
        float  e32 = __int_as_float(__float_as_int(p32) + (i << 23));  // *2^i
        // (2^t - 1)/t  Taylor, f32:
        float P5 = fmaf(t32, 1.5403530e-4f, 1.3333558e-3f);
        P5 = fmaf(t32, P5, 9.6181291e-3f);
        P5 = fmaf(t32, P5, 5.5504109e-2f);
        P5 = fmaf(t32, P5, 2.4022651e-1f);
        P5 = fmaf(t32, P5, 6.9314718e-1f);
        float em1 = t32 * P5;                    // 2^t - 1, full rel precision
        float den_a = fmaf(Q32, e32, P32);
        float den_b = fmaf(1e-8f, e32, em1);     // e-1+1e-8e without cancellation
        float den = (canc && (i == 0)) ? den_b : den_a;
        float num = (float)fma(Dd, Vx, Cd) * e32;
        float r0  = num * rcp32(den);
        return (fabs(Vx - fixV) < 1e-6) ? fixR32 : r0;
    };

    double V = -65.0;
    float  r = rate(V);                  // pipelined: r == DT*rate(V_cur), f32
    double g, m, h, n;                   // g = own gate (valid on even lanes)
    {
        float rbf = __int_as_float(__builtin_amdgcn_ds_swizzle(__float_as_int(r), SWZ_XOR1));
        double rd = (double)r, rbd = (double)rbf;
        g = rd / (rd + rbd);             // alpha/(alpha+beta) on even lanes
        m = swz_f64<SWZ_BC(0)>(g);
        h = swz_f64<SWZ_BC(2)>(g);
        n = swz_f64<SWZ_BC(4)>(g);
    }

    const float* __restrict__ Ip = I + (size_t)nb * TSTEPS;
    float*       __restrict__ Op = out + (size_t)nb * TSTEPS + slot;

    // r5-proven step order: xor early, V-update (old gates), gate commit,
    // broadcasts (covered by rate chain), rate last.
    auto step = [&](float It) {
        float rbf = __int_as_float(__builtin_amdgcn_ds_swizzle(__float_as_int(r), SWZ_XOR1));
        // ---- V-update from OLD gates (f64) ----
        double mm  = m * m,  mh = m * h;
        double m3h = mm * mh;
        double nn  = n * n;
        double n4  = nn * nn;
        double a   = kNa * m3h;
        double b   = kK * n4;
        double S1  = (K1 - a) - b;
        double S2  = fma(-77.0, b, fma(50.0, a, K2));
        double Vn  = fma(V, S1, fma(DTC, (double)It, S2));
        // ---- gate update on own lane (f64, rates promoted) ----
        double rd  = (double)r, rbd = (double)rbf;
        double sr  = rd + rbd;
        g = fma(-sr, g, g + rd);
        // ---- broadcast new gates (latency covered by rate chain below) ----
        m = swz_f64<SWZ_BC(0)>(g);
        h = swz_f64<SWZ_BC(2)>(g);
        n = swz_f64<SWZ_BC(4)>(g);
        // ---- next-step rate (short mixed-precision chain) ----
        r = rate(Vn);
        V = Vn;
    };

    const int NCH = TSTEPS / 8;
    float4 ia = reinterpret_cast<const float4*>(Ip)[0];
    float4 ib = reinterpret_cast<const float4*>(Ip)[1];

    for (int c = 0; c < NCH - 1; ++c) {
        const float cur[8] = {ia.x, ia.y, ia.z, ia.w, ib.x, ib.y, ib.z, ib.w};
        ia = reinterpret_cast<const float4*>(Ip)[2 * (c + 1)];
        ib = reinterpret_cast<const float4*>(Ip)[2 * (c + 1) + 1];
        float vs = 0.0f;
        #pragma unroll
        for (int j = 0; j < 8; ++j) {
            vs = (slot == j) ? (float)V : vs;   // out[p] = V after p steps
            step(cur[j]);
        }
        Op[c * 8] = vs;
    }
    // epilogue chunk: save 8 positions, step only the first 7 (I[T-1] unused)
    {
        const float cur[8] = {ia.x, ia.y, ia.z, ia.w, ib.x, ib.y, ib.z, ib.w};
        float vs = 0.0f;
        #pragma unroll
        for (int j = 0; j < 8; ++j) {
            vs = (slot == j) ? (float)V : vs;
            if (j < 7) step(cur[j]);
        }
        Op[(NCH - 1) * 8] = vs;
    }
}

extern "C" void kernel_launch(void* const* d_in, const int* in_sizes, int n_in,
                              void* d_out, int out_size, void* d_ws, size_t ws_size,
                              hipStream_t stream) {
    const float* I    = (const float*)d_in[0];
    const float* rgNa = (const float*)d_in[1];
    const float* rgK  = (const float*)d_in[2];
    const float* rgL  = (const float*)d_in[3];
    float* out = (float*)d_out;

    hh8t_kernel<<<dim3(BATCH / 8), dim3(64), 0, stream>>>(I, rgNa, rgK, rgL, out);
}